// Round 3
// baseline (3981.866 us; speedup 1.0000x reference)
//
#include <hip/hip_runtime.h>

// Stacked LSTM (4 layers, units 100/80/50/30) + dense head, fp32, B=T=512.
//
// R2 redesign:
//  - thread (p, s) owns ALL 4 GATES of unit p, k-slice s (S=8, KH=DIN4/8):
//    weight regs = 4*KH <= 96 floats -> fits the observed 128-VGPR cap
//    (R0/R1: 176 floats -> compiler reloaded weights every step).
//  - concat(h,x) stored row-INTERLEAVED {a_k,b_k} in LDS, per-s-segment
//    stride with (stride/16B) odd -> 8 s-lanes hit 8 distinct bank groups,
//    8-way broadcast within wave -> zero bank conflicts.
//  - shuffle-reduce over s (shfl_xor 1,2,4): complete z for unit p lands
//    lane-local -> cell update in-register, NO zp buffer, NO phase-2
//    threads, ONE __syncthreads per step (ping-pong LDS buffers).
//  - all fp32 (no fp32 MFMA on CDNA4; bf16 too risky for 4.4e-4 threshold).

#define T_SEQ 512
#define B_TOT 512

__device__ __forceinline__ float sigmoidf_(float x) {
    return 1.0f / (1.0f + __expf(-x));
}
__device__ __forceinline__ float tanh_fast(float x) {
    float e = __expf(2.0f * x);
    return 1.0f - 2.0f / (1.0f + e);   // saturates correctly at +-inf
}

// U: units, FI: input features, KH: k-slice per s (DIN4 = 8*KH >= U+FI).
// GEMV threads: tid < NT = 8*U. p = tid>>3 (unit), s = tid&7 (k-slice).
// Loader threads: tid in [NT, BLOCK) stage x(t+1) for both batch rows.
template<int U, int FI, int KH, int BLOCK, bool SEQ, bool FINAL>
__global__ __launch_bounds__(BLOCK)
void lstm_layer(const float* __restrict__ X,    // [B][T][FI]
                const float* __restrict__ W,    // [DIN][4U] row-major
                const float* __restrict__ Bv,   // [4U] gate order f,i,g,o
                float* __restrict__ Hout,       // [B][T][U] if SEQ
                const float* __restrict__ Wd,   // [U] (FINAL)
                const float* __restrict__ bd,   // [1] (FINAL)
                float* __restrict__ OUT)        // [B] (FINAL)
{
    constexpr int S    = 8;
    constexpr int DIN  = U + FI;
    constexpr int DIN4 = KH * S;
    static_assert(DIN4 >= DIN, "k-padding must cover DIN");
    static_assert((KH & 1) == 0, "KH even: each float4 = 2 interleaved k");
    constexpr int G  = 4 * U;
    constexpr int NT = U * S;
    static_assert(NT <= BLOCK, "GEMV threads must fit");
    // segment stride (floats): 2*KH rounded to mult of 4, with (stride/4) odd
    constexpr int ST0    = (2 * KH + 3) / 4 * 4;
    constexpr int STRIDE = (ST0 % 8 == 4) ? ST0 : ST0 + 4;
    constexpr int TOT    = STRIDE * S;

    __shared__ __align__(16) float buf[2][TOT];   // ping-pong concat(h,x), rows interleaved

    const int tid = threadIdx.x;
    const int bb  = blockIdx.x * 2;   // two batch rows per block

    const int p = tid >> 3;   // unit
    const int s = tid & 7;    // k-slice

    // ---- weights into registers: w[gate][kk] = W[(s*KH+kk)*G + gate*U + p]
    float w[4][KH];
    float bia[4] = {0.f, 0.f, 0.f, 0.f};
    if (tid < NT) {
        #pragma unroll
        for (int g = 0; g < 4; ++g) {
            #pragma unroll
            for (int kk = 0; kk < KH; ++kk) {
                const int k = s * KH + kk;
                w[g][kk] = (k < DIN) ? W[(size_t)k * G + g * U + p] : 0.0f;
            }
            if (s == 0) bia[g] = Bv[g * U + p];   // bias counted once in butterfly
        }
    }

    // per-lane LDS read base (float4 units)
    const int roff4 = (s * STRIDE) >> 2;
    // h write slot for unit p (row-pair, 8 bytes)
    const int hidx = (p / KH) * STRIDE + 2 * (p % KH);

    // ---- loader threads: j in [0, 2*FI), up to 2 per thread ----
    const int nload = BLOCK - NT;
    const int lidx  = tid - NT;

    // ---- init: zero both buffers, stage x(0) into buf[0] ----
    for (int i = tid; i < 2 * TOT; i += BLOCK) ((float*)buf)[i] = 0.0f;
    __syncthreads();
    if (tid >= NT) {
        #pragma unroll
        for (int rep = 0; rep < 2; ++rep) {
            const int j = lidx + rep * nload;
            if (j < 2 * FI) {
                const int r  = (j < FI) ? 0 : 1;
                const int jj = j - r * FI;
                const int k  = U + jj;
                const int wi = (k / KH) * STRIDE + 2 * (k % KH) + r;
                buf[0][wi] = X[(size_t)(bb + r) * T_SEQ * FI + jj];
            }
        }
    }
    __syncthreads();

    float h[2] = {0.f, 0.f}, c[2] = {0.f, 0.f};

    for (int t = 0; t < T_SEQ; ++t) {
        const int cur = t & 1, nxt = cur ^ 1;

        if (tid < NT) {
            // ---- GEMV partials: 4 gates x 2 rows, k-slice s ----
            float acc[4][2];
            #pragma unroll
            for (int g = 0; g < 4; ++g) { acc[g][0] = bia[g]; acc[g][1] = bia[g]; }
            const float4* rb = (const float4*)&buf[cur][0];
            #pragma unroll
            for (int q = 0; q < KH / 2; ++q) {
                const float4 v = rb[roff4 + q];   // {a(2q), b(2q), a(2q+1), b(2q+1)}
                #pragma unroll
                for (int g = 0; g < 4; ++g) {
                    acc[g][0] += w[g][2*q]   * v.x;
                    acc[g][1] += w[g][2*q]   * v.y;
                    acc[g][0] += w[g][2*q+1] * v.z;
                    acc[g][1] += w[g][2*q+1] * v.w;
                }
            }
            // ---- butterfly over s: every lane gets full z for unit p ----
            #pragma unroll
            for (int m = 1; m < 8; m <<= 1) {
                #pragma unroll
                for (int g = 0; g < 4; ++g) {
                    acc[g][0] += __shfl_xor(acc[g][0], m, 64);
                    acc[g][1] += __shfl_xor(acc[g][1], m, 64);
                }
            }
            // ---- cell update (replicated across the 8 s-lanes) ----
            #pragma unroll
            for (int r = 0; r < 2; ++r) {
                const float F  = sigmoidf_(acc[0][r]);
                const float I  = sigmoidf_(acc[1][r]);
                const float Gv = tanh_fast(acc[2][r]);
                const float O  = sigmoidf_(acc[3][r]);
                c[r] = F * c[r] + I * Gv;
                h[r] = O * tanh_fast(c[r]);
            }
            // lane s==0 writes the h pair into the NEXT buffer
            if (s == 0) {
                *(float2*)&buf[nxt][hidx] = make_float2(h[0], h[1]);
            }
            if constexpr (SEQ) {   // lanes s==2/3 stream h to global
                if (s == 2) Hout[((size_t)bb       * T_SEQ + t) * U + p] = h[0];
                if (s == 3) Hout[((size_t)(bb + 1) * T_SEQ + t) * U + p] = h[1];
            }
        } else if (t + 1 < T_SEQ) {
            // ---- loaders stage x(t+1) into the NEXT buffer ----
            #pragma unroll
            for (int rep = 0; rep < 2; ++rep) {
                const int j = lidx + rep * nload;
                if (j < 2 * FI) {
                    const int r  = (j < FI) ? 0 : 1;
                    const int jj = j - r * FI;
                    const int k  = U + jj;
                    const int wi = (k / KH) * STRIDE + 2 * (k % KH) + r;
                    buf[nxt][wi] = X[(size_t)(bb + r) * T_SEQ * FI + (size_t)(t + 1) * FI + jj];
                }
            }
        }
        __syncthreads();
    }

    if constexpr (FINAL) {
        // dense head: out[b] = sum_p h[p]*Wd[p] + bd
        if (tid < NT && s == 0) {
            buf[0][2 * p]     = h[0] * Wd[p];
            buf[0][2 * p + 1] = h[1] * Wd[p];
        }
        __syncthreads();
        if (tid < 2) {
            float acc = bd[0];
            for (int u = 0; u < U; ++u) acc += buf[0][2 * u + tid];
            OUT[bb + tid] = acc;
        }
    }
}

extern "C" void kernel_launch(void* const* d_in, const int* in_sizes, int n_in,
                              void* d_out, int out_size, void* d_ws, size_t ws_size,
                              hipStream_t stream)
{
    const float* x    = (const float*)d_in[0];
    const float* W0   = (const float*)d_in[1];
    const float* b0   = (const float*)d_in[2];
    const float* W1   = (const float*)d_in[3];
    const float* b1   = (const float*)d_in[4];
    const float* W2   = (const float*)d_in[5];
    const float* b2   = (const float*)d_in[6];
    const float* W3   = (const float*)d_in[7];
    const float* b3   = (const float*)d_in[8];
    const float* Wout = (const float*)d_in[9];
    const float* bout = (const float*)d_in[10];
    float* out = (float*)d_out;

    float* H0 = (float*)d_ws;                              // [512*512*100]
    float* H1 = H0 + (size_t)B_TOT * T_SEQ * 100;          // [512*512*80]
    float* H2 = (float*)d_ws;                              // reuses H0 slot

    const dim3 grid(B_TOT / 2);

    // <U, FI, KH, BLOCK, SEQ, FINAL>   (DIN4 = 8*KH)
    hipLaunchKernelGGL((lstm_layer<100,  64, 22, 960, true,  false>),
                       grid, dim3(960), 0, stream, x,  W0, b0, H0, nullptr, nullptr, nullptr);
    hipLaunchKernelGGL((lstm_layer< 80, 100, 24, 768, true,  false>),
                       grid, dim3(768), 0, stream, H0, W1, b1, H1, nullptr, nullptr, nullptr);
    hipLaunchKernelGGL((lstm_layer< 50,  80, 18, 512, true,  false>),
                       grid, dim3(512), 0, stream, H1, W2, b2, H2, nullptr, nullptr, nullptr);
    hipLaunchKernelGGL((lstm_layer< 30,  50, 10, 384, false, true >),
                       grid, dim3(384), 0, stream, H2, W3, b3, nullptr, Wout, bout, out);
}

// Round 4
// 1955.102 us; speedup vs baseline: 2.0367x; 2.0367x over previous
//
#include <hip/hip_runtime.h>

// Stacked LSTM (4 layers, units 100/80/50/30) + dense head, fp32, B=T=512.
//
// R3: VGPR-cap-aware redesign.
//   Cap model (from R0/R1/R2 counters): cap = 512 / ceil(resident_waves/4),
//   occupancy computed in whole-workgroup units. ONLY an exactly-8-wave
//   block with __launch_bounds__(512,2) (or 4-wave with (256,2)) yields the
//   256-VGPR cap. R0/R1 (448thr -> 128 cap) and R2 (960thr -> 64 cap) both
//   spilled their weight arrays; weights have never actually been resident.
//
//   - thread (p=tid%U, s=tid/U) owns all 4 gates of unit p, k-slice s.
//     weights w[4][KH] = 40..144 floats, statically indexed, under the cap.
//   - s-major layout: all 64 lanes of a wave share s -> ds_read_b128 is a
//     full-wave BROADCAST (same address) -> ~3cyc/instr, zero conflicts.
//   - z partials: one float4 per (s,row) with 4 gates packed; cell thread
//     (u=p, r=s<2) reads S float4s, adds bias, updates c,h in registers.
//   - two barriers/step; ping-pong concat(h,x) buffers; x(t+1) prefetched
//     by the same threads (global->reg early, reg->LDS late, T14).
//   - all fp32 (no fp32 MFMA on CDNA4; bf16 risks 512-step error growth vs
//     the 4.4e-4 threshold).

#define T_SEQ 512
#define B_TOT 512

__device__ __forceinline__ float sigmoidf_(float x) {
    return 1.0f / (1.0f + __expf(-x));
}
__device__ __forceinline__ float tanh_fast(float x) {
    float e = __expf(2.0f * x);
    return 1.0f - 2.0f / (1.0f + e);   // saturates correctly at +-inf
}

// U: units, FI: input feats, S: k-slices, KH: k per slice (DIN4 = S*KH).
template<int U, int FI, int S, int KH, int BLOCK, bool SEQ, bool FINAL>
__global__ __launch_bounds__(BLOCK, 2)
void lstm_layer(const float* __restrict__ X,    // [B][T][FI]
                const float* __restrict__ W,    // [DIN][4U] row-major
                const float* __restrict__ Bv,   // [4U] gate order f,i,g,o
                float* __restrict__ Hout,       // [B][T][U] if SEQ
                const float* __restrict__ Wd,   // [U] (FINAL)
                const float* __restrict__ bd,   // [1] (FINAL)
                float* __restrict__ OUT)        // [B] (FINAL)
{
    constexpr int DIN  = U + FI;
    constexpr int DIN4 = S * KH;
    static_assert(DIN4 >= DIN, "k-padding must cover DIN");
    static_assert((KH & 1) == 0, "KH even: one float4 = 2 k x 2 rows");
    constexpr int G  = 4 * U;
    constexpr int NT = S * U;
    static_assert(NT <= BLOCK, "GEMV threads must fit");
    static_assert(NT >= 2 * FI, "prefetch threads must be GEMV threads");
    constexpr int TOT = 2 * DIN4;

    __shared__ __align__(16) float buf[2][TOT];      // {a_k,b_k} interleaved
    __shared__ __align__(16) float zp[S * 2 * U * 4]; // [s][row][u][gate]

    const int tid = threadIdx.x;
    const int bb  = blockIdx.x * 2;      // two batch rows per block

    const int p = tid % U;               // unit
    const int s = tid / U;               // k-slice (GEMV threads: tid < NT)

    // ---- weights into registers (once; reused 512 steps) ----
    float w[4][KH];
    if (tid < NT) {
        #pragma unroll
        for (int g = 0; g < 4; ++g) {
            #pragma unroll
            for (int kk = 0; kk < KH; ++kk) {
                const int k = s * KH + kk;
                w[g][kk] = (k < DIN) ? W[(size_t)k * G + g * U + p] : 0.0f;
            }
        }
    }

    // ---- cell threads: tid < 2U -> (u = p, r = s in {0,1}) ----
    float cb4[4] = {0.f, 0.f, 0.f, 0.f};
    if (tid < 2 * U) {
        #pragma unroll
        for (int g = 0; g < 4; ++g) cb4[g] = Bv[g * U + p];
    }
    float hreg = 0.0f, creg = 0.0f;
    float wdreg = 0.0f;
    if constexpr (FINAL) { if (tid < 2 * U) wdreg = Wd[p]; }

    // ---- x-prefetch mapping (tid < 2*FI, all are GEMV threads) ----
    const int xr = (tid < FI) ? 0 : 1;
    const int xj = tid - xr * FI;
    const float* Xrow = X + (size_t)(bb + xr) * T_SEQ * FI + xj;
    const int xwi = 2 * (U + xj) + xr;

    // ---- init: zero both buffers (h=0 + k-pad), stage x(0) ----
    for (int i = tid; i < 2 * TOT; i += BLOCK) ((float*)buf)[i] = 0.0f;
    __syncthreads();
    if (tid < 2 * FI) buf[0][xwi] = Xrow[0];
    __syncthreads();

    const int rbase = s * (KH / 2);      // per-lane f4 read base

    for (int t = 0; t < T_SEQ; ++t) {
        const int cur = t & 1, nxt = cur ^ 1;

        // prefetch x(t+1) global->reg; retires under the GEMV
        float xpre = 0.0f;
        const bool do_x = (tid < 2 * FI) && (t + 1 < T_SEQ);
        if (do_x) xpre = Xrow[(size_t)(t + 1) * FI];

        // ---- phase 1: GEMV partials ----
        if (tid < NT) {
            float a0 = 0.f, a1 = 0.f, a2 = 0.f, a3 = 0.f;   // row 0, gates f,i,g,o
            float b0 = 0.f, b1 = 0.f, b2 = 0.f, b3 = 0.f;   // row 1
            const float4* rb = (const float4*)buf[cur];
            #pragma unroll
            for (int q = 0; q < KH / 2; ++q) {
                const float4 v = rb[rbase + q];  // {a(2q), b(2q), a(2q+1), b(2q+1)}
                a0 += w[0][2*q] * v.x; b0 += w[0][2*q] * v.y;
                a1 += w[1][2*q] * v.x; b1 += w[1][2*q] * v.y;
                a2 += w[2][2*q] * v.x; b2 += w[2][2*q] * v.y;
                a3 += w[3][2*q] * v.x; b3 += w[3][2*q] * v.y;
                a0 += w[0][2*q+1] * v.z; b0 += w[0][2*q+1] * v.w;
                a1 += w[1][2*q+1] * v.z; b1 += w[1][2*q+1] * v.w;
                a2 += w[2][2*q+1] * v.z; b2 += w[2][2*q+1] * v.w;
                a3 += w[3][2*q+1] * v.z; b3 += w[3][2*q+1] * v.w;
            }
            float4* zq = (float4*)zp;
            zq[(s * 2 + 0) * U + p] = make_float4(a0, a1, a2, a3);
            zq[(s * 2 + 1) * U + p] = make_float4(b0, b1, b2, b3);
        }
        // stage x(t+1) reg->LDS (disjoint region from phase-2 h writes)
        if (do_x) buf[nxt][xwi] = xpre;
        __syncthreads();

        // ---- phase 2: reduce + cell update ----
        if (tid < 2 * U) {
            float z0 = cb4[0], z1 = cb4[1], z2 = cb4[2], z3 = cb4[3];
            const float4* zq = (const float4*)zp;
            #pragma unroll
            for (int ss = 0; ss < S; ++ss) {
                const float4 v = zq[(ss * 2 + s) * U + p];
                z0 += v.x; z1 += v.y; z2 += v.z; z3 += v.w;
            }
            const float F  = sigmoidf_(z0);
            const float I  = sigmoidf_(z1);
            const float Gv = tanh_fast(z2);
            const float O  = sigmoidf_(z3);
            creg = F * creg + I * Gv;
            hreg = O * tanh_fast(creg);
            buf[nxt][2 * p + s] = hreg;
            if constexpr (SEQ) {
                Hout[((size_t)(bb + s) * T_SEQ + t) * U + p] = hreg;
            }
        }
        __syncthreads();
    }

    if constexpr (FINAL) {
        if (tid < 2 * U) buf[0][2 * p + s] = hreg * wdreg;
        __syncthreads();
        if (tid < 2) {
            float acc = bd[0];
            for (int u = 0; u < U; ++u) acc += buf[0][2 * u + tid];
            OUT[bb + tid] = acc;
        }
    }
}

extern "C" void kernel_launch(void* const* d_in, const int* in_sizes, int n_in,
                              void* d_out, int out_size, void* d_ws, size_t ws_size,
                              hipStream_t stream)
{
    const float* x    = (const float*)d_in[0];
    const float* W0   = (const float*)d_in[1];
    const float* b0   = (const float*)d_in[2];
    const float* W1   = (const float*)d_in[3];
    const float* b1   = (const float*)d_in[4];
    const float* W2   = (const float*)d_in[5];
    const float* b2   = (const float*)d_in[6];
    const float* W3   = (const float*)d_in[7];
    const float* b3   = (const float*)d_in[8];
    const float* Wout = (const float*)d_in[9];
    const float* bout = (const float*)d_in[10];
    float* out = (float*)d_out;

    float* H0 = (float*)d_ws;                         // [512*512*100]
    float* H1 = H0 + (size_t)B_TOT * T_SEQ * 100;     // [512*512*80]
    float* H2 = (float*)d_ws;                         // reuses H0 slot

    const dim3 grid(B_TOT / 2);

    // <U, FI, S, KH, BLOCK, SEQ, FINAL>
    // block=512 (8 waves) + bounds(512,2) -> 1 WG/CU -> 256-VGPR cap.
    // block=256 (4 waves) + bounds(256,2) -> 2 WG/CU -> 256-VGPR cap.
    hipLaunchKernelGGL((lstm_layer<100,  64, 5, 36, 512, true,  false>),
                       grid, dim3(512), 0, stream, x,  W0, b0, H0, nullptr, nullptr, nullptr);
    hipLaunchKernelGGL((lstm_layer< 80, 100, 6, 30, 512, true,  false>),
                       grid, dim3(512), 0, stream, H0, W1, b1, H1, nullptr, nullptr, nullptr);
    hipLaunchKernelGGL((lstm_layer< 50,  80, 5, 26, 256, true,  false>),
                       grid, dim3(256), 0, stream, H1, W2, b2, H2, nullptr, nullptr, nullptr);
    hipLaunchKernelGGL((lstm_layer< 30,  50, 8, 10, 256, false, true >),
                       grid, dim3(256), 0, stream, H2, W3, b3, nullptr, Wout, bout, out);
}

// Round 5
// 1868.854 us; speedup vs baseline: 2.1306x; 1.0462x over previous
//
#include <hip/hip_runtime.h>

// Stacked LSTM (4 layers, units 100/80/50/30) + dense head, fp32, B=T=512.
//
// R4: pin weights in VGPRs.
//   R3 counters showed VGPR_Count=108 < 144 weight floats: since W is
//   const __restrict__, LLVM marks the weight loads invariant and the
//   register allocator REMATERIALIZES them inside the 512-step loop
//   (re-streaming weights from L1/L2 every step; VALUBusy stuck ~61%).
//   Fix: pass every loaded weight through an empty inline asm
//   (asm volatile("" : "+v"(x))) -> opaque def, not rematerializable,
//   must stay resident. Cap is 256 VGPR (8-wave block, bounds(512,2)),
//   need ~200.
//
//   Structure unchanged from R3:
//   - thread (p=tid%U, s=tid/U) owns all 4 gates of unit p, k-slice s.
//   - s-major: all 64 lanes of a wave share s -> ds_read_b128 broadcasts.
//   - z partials as packed float4 (4 gates); cell thread reduces S of them.
//   - two barriers/step; ping-pong concat(h,x); x(t+1) prefetch (T14).
//   - all fp32 (no fp32 MFMA on CDNA4; bf16 risks 512-step error growth).

#define T_SEQ 512
#define B_TOT 512

#define PIN(x) asm volatile("" : "+v"(x))

__device__ __forceinline__ float sigmoidf_(float x) {
    return 1.0f / (1.0f + __expf(-x));
}
__device__ __forceinline__ float tanh_fast(float x) {
    float e = __expf(2.0f * x);
    return 1.0f - 2.0f / (1.0f + e);   // saturates correctly at +-inf
}

// U: units, FI: input feats, S: k-slices, KH: k per slice (DIN4 = S*KH).
template<int U, int FI, int S, int KH, int BLOCK, bool SEQ, bool FINAL>
__global__ __launch_bounds__(BLOCK, 2)
void lstm_layer(const float* __restrict__ X,    // [B][T][FI]
                const float* __restrict__ W,    // [DIN][4U] row-major
                const float* __restrict__ Bv,   // [4U] gate order f,i,g,o
                float* __restrict__ Hout,       // [B][T][U] if SEQ
                const float* __restrict__ Wd,   // [U] (FINAL)
                const float* __restrict__ bd,   // [1] (FINAL)
                float* __restrict__ OUT)        // [B] (FINAL)
{
    constexpr int DIN  = U + FI;
    constexpr int DIN4 = S * KH;
    static_assert(DIN4 >= DIN, "k-padding must cover DIN");
    static_assert((KH & 1) == 0, "KH even: one float4 = 2 k x 2 rows");
    constexpr int G  = 4 * U;
    constexpr int NT = S * U;
    static_assert(NT <= BLOCK, "GEMV threads must fit");
    static_assert(NT >= 2 * FI, "prefetch threads must be GEMV threads");
    constexpr int TOT = 2 * DIN4;

    __shared__ __align__(16) float buf[2][TOT];       // {a_k,b_k} interleaved
    __shared__ __align__(16) float zp[S * 2 * U * 4]; // [s][row][u][gate]

    const int tid = threadIdx.x;
    const int bb  = blockIdx.x * 2;      // two batch rows per block

    const int p = tid % U;               // unit
    const int s = tid / U;               // k-slice (GEMV threads: tid < NT)

    // ---- weights into registers (once; reused 512 steps), then PIN ----
    float w[4][KH];
    if (tid < NT) {
        #pragma unroll
        for (int g = 0; g < 4; ++g) {
            #pragma unroll
            for (int kk = 0; kk < KH; ++kk) {
                const int k = s * KH + kk;
                w[g][kk] = (k < DIN) ? W[(size_t)k * G + g * U + p] : 0.0f;
            }
        }
        #pragma unroll
        for (int g = 0; g < 4; ++g) {
            #pragma unroll
            for (int kk = 0; kk < KH; ++kk) PIN(w[g][kk]);
        }
    }

    // ---- cell threads: tid < 2U -> (u = p, r = s in {0,1}) ----
    float cb4[4] = {0.f, 0.f, 0.f, 0.f};
    if (tid < 2 * U) {
        #pragma unroll
        for (int g = 0; g < 4; ++g) cb4[g] = Bv[g * U + p];
    }
    float hreg = 0.0f, creg = 0.0f;
    float wdreg = 0.0f;
    if constexpr (FINAL) { if (tid < 2 * U) wdreg = Wd[p]; }

    // ---- x-prefetch mapping (tid < 2*FI, all are GEMV threads) ----
    const int xr = (tid < FI) ? 0 : 1;
    const int xj = tid - xr * FI;
    const float* Xrow = X + (size_t)(bb + xr) * T_SEQ * FI + xj;
    const int xwi = 2 * (U + xj) + xr;

    // ---- init: zero both buffers (h=0 + k-pad), stage x(0) ----
    for (int i = tid; i < 2 * TOT; i += BLOCK) ((float*)buf)[i] = 0.0f;
    __syncthreads();
    if (tid < 2 * FI) buf[0][xwi] = Xrow[0];
    __syncthreads();

    const int rbase = s * (KH / 2);      // per-lane f4 read base

    for (int t = 0; t < T_SEQ; ++t) {
        const int cur = t & 1, nxt = cur ^ 1;

        // prefetch x(t+1) global->reg; retires under the GEMV
        float xpre = 0.0f;
        const bool do_x = (tid < 2 * FI) && (t + 1 < T_SEQ);
        if (do_x) xpre = Xrow[(size_t)(t + 1) * FI];

        // ---- phase 1: GEMV partials ----
        if (tid < NT) {
            float a0 = 0.f, a1 = 0.f, a2 = 0.f, a3 = 0.f;   // row 0, gates f,i,g,o
            float b0 = 0.f, b1 = 0.f, b2 = 0.f, b3 = 0.f;   // row 1
            const float4* rb = (const float4*)buf[cur];
            #pragma unroll
            for (int q = 0; q < KH / 2; ++q) {
                const float4 v = rb[rbase + q];  // {a(2q), b(2q), a(2q+1), b(2q+1)}
                a0 += w[0][2*q] * v.x; b0 += w[0][2*q] * v.y;
                a1 += w[1][2*q] * v.x; b1 += w[1][2*q] * v.y;
                a2 += w[2][2*q] * v.x; b2 += w[2][2*q] * v.y;
                a3 += w[3][2*q] * v.x; b3 += w[3][2*q] * v.y;
                a0 += w[0][2*q+1] * v.z; b0 += w[0][2*q+1] * v.w;
                a1 += w[1][2*q+1] * v.z; b1 += w[1][2*q+1] * v.w;
                a2 += w[2][2*q+1] * v.z; b2 += w[2][2*q+1] * v.w;
                a3 += w[3][2*q+1] * v.z; b3 += w[3][2*q+1] * v.w;
            }
            float4* zq = (float4*)zp;
            zq[(s * 2 + 0) * U + p] = make_float4(a0, a1, a2, a3);
            zq[(s * 2 + 1) * U + p] = make_float4(b0, b1, b2, b3);
        }
        // stage x(t+1) reg->LDS (disjoint region from phase-2 h writes)
        if (do_x) buf[nxt][xwi] = xpre;
        __syncthreads();

        // ---- phase 2: reduce + cell update ----
        if (tid < 2 * U) {
            float z0 = cb4[0], z1 = cb4[1], z2 = cb4[2], z3 = cb4[3];
            const float4* zq = (const float4*)zp;
            #pragma unroll
            for (int ss = 0; ss < S; ++ss) {
                const float4 v = zq[(ss * 2 + s) * U + p];
                z0 += v.x; z1 += v.y; z2 += v.z; z3 += v.w;
            }
            const float F  = sigmoidf_(z0);
            const float I  = sigmoidf_(z1);
            const float Gv = tanh_fast(z2);
            const float O  = sigmoidf_(z3);
            creg = F * creg + I * Gv;
            hreg = O * tanh_fast(creg);
            buf[nxt][2 * p + s] = hreg;
            if constexpr (SEQ) {
                Hout[((size_t)(bb + s) * T_SEQ + t) * U + p] = hreg;
            }
        }
        __syncthreads();
    }

    if constexpr (FINAL) {
        if (tid < 2 * U) buf[0][2 * p + s] = hreg * wdreg;
        __syncthreads();
        if (tid < 2) {
            float acc = bd[0];
            for (int u = 0; u < U; ++u) acc += buf[0][2 * u + tid];
            OUT[bb + tid] = acc;
        }
    }
}

extern "C" void kernel_launch(void* const* d_in, const int* in_sizes, int n_in,
                              void* d_out, int out_size, void* d_ws, size_t ws_size,
                              hipStream_t stream)
{
    const float* x    = (const float*)d_in[0];
    const float* W0   = (const float*)d_in[1];
    const float* b0   = (const float*)d_in[2];
    const float* W1   = (const float*)d_in[3];
    const float* b1   = (const float*)d_in[4];
    const float* W2   = (const float*)d_in[5];
    const float* b2   = (const float*)d_in[6];
    const float* W3   = (const float*)d_in[7];
    const float* b3   = (const float*)d_in[8];
    const float* Wout = (const float*)d_in[9];
    const float* bout = (const float*)d_in[10];
    float* out = (float*)d_out;

    float* H0 = (float*)d_ws;                         // [512*512*100]
    float* H1 = H0 + (size_t)B_TOT * T_SEQ * 100;     // [512*512*80]
    float* H2 = (float*)d_ws;                         // reuses H0 slot

    const dim3 grid(B_TOT / 2);

    // <U, FI, S, KH, BLOCK, SEQ, FINAL>
    // block=512 (8 waves) + bounds(512,2) -> 1 WG/CU -> 256-VGPR cap.
    // block=256 (4 waves) + bounds(256,2) -> 2 WG/CU -> 256-VGPR cap.
    hipLaunchKernelGGL((lstm_layer<100,  64, 5, 36, 512, true,  false>),
                       grid, dim3(512), 0, stream, x,  W0, b0, H0, nullptr, nullptr, nullptr);
    hipLaunchKernelGGL((lstm_layer< 80, 100, 6, 30, 512, true,  false>),
                       grid, dim3(512), 0, stream, H0, W1, b1, H1, nullptr, nullptr, nullptr);
    hipLaunchKernelGGL((lstm_layer< 50,  80, 5, 26, 256, true,  false>),
                       grid, dim3(256), 0, stream, H1, W2, b2, H2, nullptr, nullptr, nullptr);
    hipLaunchKernelGGL((lstm_layer< 30,  50, 8, 10, 256, false, true >),
                       grid, dim3(256), 0, stream, H2, W3, b3, nullptr, Wout, bout, out);
}